// Round 1
// baseline (2041.611 us; speedup 1.0000x reference)
//
#include <hip/hip_runtime.h>

// CapsNet forward, fp32 reference-faithful implementation (round 0: correctness).
// Pipeline: conv1+relu -> capsconv (direct, LDS-tiled) -> squash -> routing x3
// Routing never materializes u_hat: s and uv are computed via re-associated GEMMs.

#define NB 180

__global__ void zero_f32(float* __restrict__ p, int n){
    int i = blockIdx.x * 256 + threadIdx.x;
    if (i < n) p[i] = 0.f;
}

// caps_w flat [oc=256][ick=20736] -> wT [ick][oc]
__global__ __launch_bounds__(1024) void transpose_w(const float* __restrict__ w, float* __restrict__ wT){
    __shared__ float tile[32][33];
    int ick0 = blockIdx.x * 32, oc0 = blockIdx.y * 32;
    int tx = threadIdx.x, ty = threadIdx.y;
    tile[ty][tx] = w[(oc0 + ty) * 20736 + ick0 + tx];
    __syncthreads();
    wT[(ick0 + ty) * 256 + oc0 + tx] = tile[tx][ty];
}

// x [180][28*28] * w [256][81] -> h [180][256][20][20], bias+relu
// grid (180, 8), block 640 = 20 oy * 32 oc
__global__ __launch_bounds__(640) void conv1_kernel(const float* __restrict__ x, const float* __restrict__ w,
                                                    const float* __restrict__ bias, float* __restrict__ h){
    __shared__ float xs[784];
    __shared__ float ws[32 * 81];
    int b = blockIdx.x, ocg = blockIdx.y;
    int t = threadIdx.x;
    for (int i = t; i < 784; i += 640) xs[i] = x[b * 784 + i];
    for (int i = t; i < 32 * 81; i += 640) ws[i] = w[(ocg * 32) * 81 + i];
    __syncthreads();
    int oy = t % 20, ocl = t / 20;
    int oc = ocg * 32 + ocl;
    float acc[20];
#pragma unroll
    for (int i = 0; i < 20; i++) acc[i] = 0.f;
    for (int ky = 0; ky < 9; ky++){
        float xr[28];
        const float* row = &xs[(oy + ky) * 28];
#pragma unroll
        for (int i = 0; i < 28; i += 4){
            float4 v4 = *(const float4*)(row + i);
            xr[i] = v4.x; xr[i+1] = v4.y; xr[i+2] = v4.z; xr[i+3] = v4.w;
        }
#pragma unroll
        for (int kx = 0; kx < 9; kx++){
            float wv = ws[ocl * 81 + ky * 9 + kx];
#pragma unroll
            for (int ox = 0; ox < 20; ox++) acc[ox] += wv * xr[ox + kx];
        }
    }
    float bv = bias[oc];
    float* out = &h[((b * 256 + oc) * 400) + oy * 20];
#pragma unroll
    for (int ox = 0; ox < 20; ox++){
        float v = acc[ox] + bv;
        out[ox] = v > 0.f ? v : 0.f;
    }
}

// h [180][256][400] * wT [20736][256] stride-2 conv -> u [180][256][36] (+bias)
// grid (180, 4), block 384 = 64 oc * 6 oy
__global__ __launch_bounds__(384) void capsconv_kernel(const float* __restrict__ h, const float* __restrict__ wT,
                                                       const float* __restrict__ bias, float* __restrict__ u){
    __shared__ float hs[16 * 400]; // 25.6 KB
    int b = blockIdx.x;
    int oc = blockIdx.y * 64 + (threadIdx.x & 63);
    int oy = threadIdx.x >> 6; // 0..5
    float acc[6] = {0.f, 0.f, 0.f, 0.f, 0.f, 0.f};
    for (int ic0 = 0; ic0 < 256; ic0 += 16){
        __syncthreads();
        const float* src = &h[(b * 256 + ic0) * 400];
        for (int i = threadIdx.x; i < 1600; i += 384)
            ((float4*)hs)[i] = ((const float4*)src)[i];
        __syncthreads();
        for (int ic = 0; ic < 16; ic++){
            const float* hrow_base = &hs[ic * 400];
            for (int ky = 0; ky < 9; ky++){
                float xr[20];
                const float* row = hrow_base + (2 * oy + ky) * 20;
#pragma unroll
                for (int i = 0; i < 20; i += 4){
                    float4 v4 = *(const float4*)(row + i);
                    xr[i] = v4.x; xr[i+1] = v4.y; xr[i+2] = v4.z; xr[i+3] = v4.w;
                }
                const float* wrow = &wT[((ic0 + ic) * 81 + ky * 9) * 256 + oc];
#pragma unroll
                for (int kx = 0; kx < 9; kx++){
                    float wv = wrow[kx * 256];
#pragma unroll
                    for (int ox = 0; ox < 6; ox++) acc[ox] += wv * xr[2 * ox + kx];
                }
            }
        }
    }
    float bv = bias[oc];
    float* out = &u[b * 9216 + oc * 36 + oy * 6];
#pragma unroll
    for (int ox = 0; ox < 6; ox++) out[ox] = acc[ox] + bv;
}

// in-place squash over each contiguous 1152-block (b,k). scale = 1/(sqrt(ssq)+ssq)
__global__ __launch_bounds__(192) void squash_u(float* __restrict__ u){
    __shared__ float red[3];
    int base = blockIdx.x * 1152;
    int t = threadIdx.x;
    float vals[6];
    float ssq = 0.f;
#pragma unroll
    for (int j = 0; j < 6; j++){ float v = u[base + t + j * 192]; vals[j] = v; ssq += v * v; }
#pragma unroll
    for (int off = 32; off; off >>= 1) ssq += __shfl_down(ssq, off, 64);
    if ((t & 63) == 0) red[t >> 6] = ssq;
    __syncthreads();
    float tot = red[0] + red[1] + red[2];
    float scale = 1.f / (sqrtf(tot) + tot);
#pragma unroll
    for (int j = 0; j < 6; j++) u[base + t + j * 192] = vals[j] * scale;
}

// u [b][ki=9216] -> uT [ki][b=180]
__global__ __launch_bounds__(1024) void transpose_u(const float* __restrict__ u, float* __restrict__ uT){
    __shared__ float tile[32][33];
    int ki0 = blockIdx.x * 32, b0 = blockIdx.y * 32;
    int tx = threadIdx.x, ty = threadIdx.y;
    int b = b0 + ty;
    if (b < NB) tile[ty][tx] = u[b * 9216 + ki0 + tx];
    __syncthreads();
    int bw = b0 + tx;
    if (bw < NB) uT[(ki0 + ty) * NB + bw] = tile[tx][ty];
}

// c[i][o] = softmax over o of b_ij[i][o]
__global__ void softmax_b(const float* __restrict__ bij, float* __restrict__ c){
    int i = blockIdx.x * 256 + threadIdx.x;
    if (i >= 1152) return;
    float v[10]; float m = -1e30f;
#pragma unroll
    for (int o = 0; o < 10; o++){ v[o] = bij[i * 10 + o]; m = fmaxf(m, v[o]); }
    float sum = 0.f;
#pragma unroll
    for (int o = 0; o < 10; o++){ v[o] = __expf(v[o] - m); sum += v[o]; }
    float inv = 1.f / sum;
#pragma unroll
    for (int o = 0; o < 10; o++) c[i * 10 + o] = v[o] * inv;
}

// cw2[o][ki][d] = c[i][o] * W[i][o][d][k], ki = k*1152+i
__global__ void build_cw2(const float* __restrict__ c, const float* __restrict__ Wr, float* __restrict__ cw2){
    int t = blockIdx.x * 256 + threadIdx.x; // < 1474560
    int d = t & 15;
    int ki = (t >> 4) % 9216;
    int o = t / (9216 * 16);
    int k = ki / 1152, i = ki % 1152;
    cw2[t] = c[i * 10 + o] * Wr[(i * 10 + o) * 128 + d * 8 + k];
}

// split-K partials: part[o][kc][b][d] = sum over 512 ki of cw2[o][ki][d]*uT[ki][b]
// grid (10, 18), block 192 (180 active lanes = b)
__global__ __launch_bounds__(192) void s_partial(const float* __restrict__ cw2, const float* __restrict__ uT,
                                                 float* __restrict__ part){
    int o = blockIdx.x, kc = blockIdx.y;
    int t = threadIdx.x;
    if (t >= NB) return;
    float acc[16];
#pragma unroll
    for (int d = 0; d < 16; d++) acc[d] = 0.f;
    int ki0 = kc * 512;
    const float* cwp = cw2 + (o * 9216 + ki0) * 16;
    const float* up = uT + ki0 * NB;
    for (int j = 0; j < 512; j++){
        float uv = up[j * NB + t];
#pragma unroll
        for (int d = 0; d < 16; d++) acc[d] += uv * cwp[j * 16 + d];
    }
    float* pp = part + ((o * 18 + kc) * NB + t) * 16;
#pragma unroll
    for (int d = 0; d < 16; d++) pp[d] = acc[d];
}

// s[b][o][d] = sum_kc part[o][kc][b][d]
__global__ void s_reduce(const float* __restrict__ part, float* __restrict__ s){
    int t = blockIdx.x * 256 + threadIdx.x; // < 28800
    if (t >= 28800) return;
    int d = t & 15, o = (t >> 4) % 10, b = t / 160;
    float acc = 0.f;
    for (int kc = 0; kc < 18; kc++) acc += part[((o * 18 + kc) * NB + b) * 16 + d];
    s[t] = acc;
}

// v[b][o][d] = s * 1/(sqrt(msq)+msq), msq over o (axis=1)
__global__ void v_squash(const float* __restrict__ s, float* __restrict__ v){
    int t = blockIdx.x * 256 + threadIdx.x; // < 2880 (b,d)
    if (t >= 2880) return;
    int b = t >> 4, d = t & 15;
    const float* sp = s + b * 160 + d;
    float sv[10]; float msq = 0.f;
#pragma unroll
    for (int o = 0; o < 10; o++){ sv[o] = sp[o * 16]; msq += sv[o] * sv[o]; }
    float scale = 1.f / (sqrtf(msq) + msq);
    float* vp = v + b * 160 + d;
#pragma unroll
    for (int o = 0; o < 10; o++) vp[o * 16] = sv[o] * scale;
}

// P[ki][o*16+d] = sum_b uT[ki][b] * v[b][o][d]; grid 288, block 320 = 32 ki * 10 o
__global__ __launch_bounds__(320) void p_gemm(const float* __restrict__ uT, const float* __restrict__ v,
                                              float* __restrict__ P){
    __shared__ float vs[60 * 160]; // 38.4 KB
    int t = threadIdx.x;
    int o = t % 10, kil = t / 10;
    int ki = blockIdx.x * 32 + kil;
    float acc[16];
#pragma unroll
    for (int d = 0; d < 16; d++) acc[d] = 0.f;
    const float* up = uT + ki * NB;
    for (int b0 = 0; b0 < NB; b0 += 60){
        __syncthreads();
        for (int j = t; j < 9600; j += 320) vs[j] = v[b0 * 160 + j];
        __syncthreads();
        for (int b = 0; b < 60; b++){
            float uv = up[b0 + b];
            const float* vp = &vs[b * 160 + o * 16];
#pragma unroll
            for (int d = 0; d < 16; d++) acc[d] += uv * vp[d];
        }
    }
    float* pp = P + ki * 160 + o * 16;
#pragma unroll
    for (int d = 0; d < 16; d++) pp[d] = acc[d];
}

// b_ij[i][o] += (1/B) * sum_{d,k} W[i][o][d][k] * P[k*1152+i][o*16+d]
__global__ void uv_contract(const float* __restrict__ Wr, const float* __restrict__ P, float* __restrict__ bij){
    int t = blockIdx.x * 256 + threadIdx.x; // < 11520
    if (t >= 11520) return;
    int o = t % 10, i = t / 10;
    const float* wp = Wr + (i * 10 + o) * 128;
    float acc = 0.f;
    for (int k = 0; k < 8; k++){
        const float* pp = P + (k * 1152 + i) * 160 + o * 16;
#pragma unroll
        for (int d = 0; d < 16; d++) acc += wp[d * 8 + k] * pp[d];
    }
    bij[t] += acc * (1.0f / 180.0f);
}

extern "C" void kernel_launch(void* const* d_in, const int* in_sizes, int n_in,
                              void* d_out, int out_size, void* d_ws, size_t ws_size,
                              hipStream_t stream){
    const float* x       = (const float*)d_in[0];
    const float* conv1_w = (const float*)d_in[1];
    const float* conv1_b = (const float*)d_in[2];
    const float* caps_w  = (const float*)d_in[3];
    const float* caps_b  = (const float*)d_in[4];
    const float* Wr      = (const float*)d_in[5];
    float* out = (float*)d_out;
    float* ws  = (float*)d_ws;

    float* h    = ws;                    // 18,432,000
    float* wT   = h    + 18432000;       //  5,308,416
    float* u    = wT   + 5308416;        //  1,658,880
    float* uT   = u    + 1658880;        //  1,658,880
    float* cw2  = uT   + 1658880;        //  1,474,560
    float* part = cw2  + 1474560;        //    518,400
    float* s    = part + 518400;         //     28,800
    float* P    = s    + 28800;          //  1,474,560
    float* bij  = P    + 1474560;        //     11,520
    float* c    = bij  + 11520;          //     11,520  (total ~122.3 MB)

    zero_f32<<<45, 256, 0, stream>>>(bij, 11520);
    transpose_w<<<dim3(648, 8), dim3(32, 32), 0, stream>>>(caps_w, wT);
    conv1_kernel<<<dim3(180, 8), 640, 0, stream>>>(x, conv1_w, conv1_b, h);
    capsconv_kernel<<<dim3(180, 4), 384, 0, stream>>>(h, wT, caps_b, u);
    squash_u<<<1440, 192, 0, stream>>>(u);
    transpose_u<<<dim3(288, 6), dim3(32, 32), 0, stream>>>(u, uT);

    for (int it = 0; it < 3; ++it){
        softmax_b<<<5, 256, 0, stream>>>(bij, c);
        build_cw2<<<5760, 256, 0, stream>>>(c, Wr, cw2);
        s_partial<<<dim3(10, 18), 192, 0, stream>>>(cw2, uT, part);
        s_reduce<<<113, 256, 0, stream>>>(part, s);
        v_squash<<<12, 256, 0, stream>>>(s, out);
        if (it < 2){
            p_gemm<<<288, 320, 0, stream>>>(uT, out, P);
            uv_contract<<<45, 256, 0, stream>>>(Wr, P, bij);
        }
    }
}

// Round 2
// 793.137 us; speedup vs baseline: 2.5741x; 2.5741x over previous
//
#include <hip/hip_runtime.h>
#include <hip/hip_bf16.h>

#define NB 180
typedef __attribute__((ext_vector_type(8))) short short8;
typedef __attribute__((ext_vector_type(4))) float f32x4;
typedef unsigned short ushort_t;

__global__ void zero_f32(float* __restrict__ p, int n){
    int i = blockIdx.x * 256 + threadIdx.x;
    if (i < n) p[i] = 0.f;
}

// u[b*9216 + oc*36 + pos] = caps_b[oc]
__global__ void init_u(float* __restrict__ u, const float* __restrict__ caps_b){
    int i = blockIdx.x * 256 + threadIdx.x;
    if (i < 1658880) u[i] = caps_b[(i / 36) & 255];
}

// caps_w fp32 [oc256][ic256][ky9][kx9] -> bpack bf16 [gk=kk*32+ic>>3][oc][j=ic&7]
__global__ void build_bpack(const float* __restrict__ w, __hip_bfloat16* __restrict__ bpack){
    int t = blockIdx.x * 256 + threadIdx.x;   // 5,308,416 total
    int j = t & 7; int oc = (t >> 3) & 255; int gk = t >> 11; // 0..2591
    int kk = gk >> 5, icg = gk & 31;
    float v = w[oc * 20736 + (icg * 8 + j) * 81 + kk];
    bpack[t] = __float2bfloat16(v);
}

// conv1+relu -> hT bf16 [b][y20][x20][oc256]
// grid (180, 8), block 640 = 32 ocl * 20 oy
__global__ __launch_bounds__(640) void conv1_kernel(const float* __restrict__ x, const float* __restrict__ w,
                                                    const float* __restrict__ bias, __hip_bfloat16* __restrict__ hT){
    __shared__ float xs[784];
    __shared__ float ws[32 * 81];
    int b = blockIdx.x, ocg = blockIdx.y;
    int t = threadIdx.x;
    for (int i = t; i < 784; i += 640) xs[i] = x[b * 784 + i];
    for (int i = t; i < 32 * 81; i += 640) ws[i] = w[ocg * 32 * 81 + i];
    __syncthreads();
    int ocl = t & 31, oy = t >> 5;
    int oc = ocg * 32 + ocl;
    float acc[20];
#pragma unroll
    for (int i = 0; i < 20; i++) acc[i] = 0.f;
    for (int ky = 0; ky < 9; ky++){
        float xr[28];
        const float* row = &xs[(oy + ky) * 28];
#pragma unroll
        for (int i = 0; i < 28; i += 4){
            float4 v4 = *(const float4*)(row + i);
            xr[i] = v4.x; xr[i+1] = v4.y; xr[i+2] = v4.z; xr[i+3] = v4.w;
        }
#pragma unroll
        for (int kx = 0; kx < 9; kx++){
            float wv = ws[ocl * 81 + ky * 9 + kx];
#pragma unroll
            for (int ox = 0; ox < 20; ox++) acc[ox] += wv * xr[ox + kx];
        }
    }
    float bv = bias[oc];
#pragma unroll
    for (int ox = 0; ox < 20; ox++){
        float v = acc[ox] + bv;
        v = v > 0.f ? v : 0.f;
        hT[((b * 20 + oy) * 20 + ox) * 256 + oc] = __float2bfloat16(v);
    }
}

// Implicit-GEMM capsconv: M=144 (4 batches, no pad) x N=256, K-chunk = one ky.
// grid (45, 9); block 768 = 12 waves (3 wm x 4 wn). atomicAdd into bias-initialized u.
__global__ __launch_bounds__(768) void capsconv_mfma(const __hip_bfloat16* __restrict__ hT,
                                                     const __hip_bfloat16* __restrict__ bpack,
                                                     float* __restrict__ u){
    __shared__ uint4 hs4[3840]; // [lb4][yy6][x20][slot8] 16B granules = 61.4 KB
    int mt = blockIdx.x;        // M-tile: batches 4*mt..4*mt+3
    int ky = blockIdx.y;        // 0..8
    int b0 = mt * 4;
    int t = threadIdx.x;
    int lane = t & 63, wid = t >> 6;
    int wm = wid >> 2, wn = wid & 3;
    int g = lane >> 4, lr = lane & 15;

    // Per-M-frag A geometry (row -> (batch, oy, ox)), constant over K.
    int pbase[3];
#pragma unroll
    for (int m = 0; m < 3; m++){
        int R = wm * 48 + m * 16 + lr;
        int lb = R / 36, pos = R - lb * 36;
        int oy = pos / 6, ox = pos - oy * 6;
        pbase[m] = (lb * 6 + oy) * 20 + 2 * ox;
    }

    f32x4 acc[3][4];
#pragma unroll
    for (int m = 0; m < 3; m++)
#pragma unroll
        for (int n = 0; n < 4; n++) acc[m][n] = (f32x4){0.f, 0.f, 0.f, 0.f};

    for (int ic0 = 0; ic0 < 256; ic0 += 64){
        __syncthreads();
        // Stage 4 batches x 6 rows (y = ky+2*yy) x 20 x 64ic, XOR-swizzled granules.
#pragma unroll
        for (int it = 0; it < 5; it++){
            int L = it * 768 + t;            // 0..3839
            int p = L >> 3, sg = L & 7;
            int lb = p / 120; int rem = p - lb * 120;
            int yy = rem / 20; int xx = rem - yy * 20;
            int srcofs = (((b0 + lb) * 20 + (ky + 2 * yy)) * 20 + xx) * 256
                       + ic0 + 8 * (sg ^ ((p >> 1) & 7));
            hs4[L] = *reinterpret_cast<const uint4*>(hT + srcofs);
        }
        __syncthreads();
        const ushort_t* hsu = reinterpret_cast<const ushort_t*>(hs4);
        for (int kx = 0; kx < 9; kx++){
#pragma unroll
            for (int ics = 0; ics < 2; ics++){
                int ksg = (ky * 9 + kx) * 8 + (ic0 >> 5) + ics;
                short8 bf[4];
#pragma unroll
                for (int n = 0; n < 4; n++){
                    int oc = wn * 64 + n * 16 + lr;
                    bf[n] = *reinterpret_cast<const short8*>(bpack + ((size_t)(ksg * 4 + g) * 256 + oc) * 8);
                }
                short8 af[3];
#pragma unroll
                for (int m = 0; m < 3; m++){
                    int p = pbase[m] + kx;
                    int slot = (ics * 4 + g) ^ ((p >> 1) & 7);
                    af[m] = *reinterpret_cast<const short8*>(hsu + p * 64 + slot * 8);
                }
#pragma unroll
                for (int m = 0; m < 3; m++)
#pragma unroll
                    for (int n = 0; n < 4; n++)
                        acc[m][n] = __builtin_amdgcn_mfma_f32_16x16x32_bf16(af[m], bf[n], acc[m][n], 0, 0, 0);
            }
        }
    }
    // Epilogue: C/D layout col=lane&15, row=(lane>>4)*4+reg (m89-verified).
#pragma unroll
    for (int m = 0; m < 3; m++){
        int Rb = wm * 48 + m * 16 + g * 4;
#pragma unroll
        for (int n = 0; n < 4; n++){
            int oc = wn * 64 + n * 16 + lr;
#pragma unroll
            for (int reg = 0; reg < 4; reg++){
                int R = Rb + reg;
                int lb = R / 36, pos = R - lb * 36;
                atomicAdd(&u[(size_t)(b0 + lb) * 9216 + oc * 36 + pos], acc[m][n][reg]);
            }
        }
    }
}

// in-place squash over each contiguous 1152-block (b,k)
__global__ __launch_bounds__(192) void squash_u(float* __restrict__ u){
    __shared__ float red[3];
    int base = blockIdx.x * 1152;
    int t = threadIdx.x;
    float vals[6];
    float ssq = 0.f;
#pragma unroll
    for (int j = 0; j < 6; j++){ float v = u[base + t + j * 192]; vals[j] = v; ssq += v * v; }
#pragma unroll
    for (int off = 32; off; off >>= 1) ssq += __shfl_down(ssq, off, 64);
    if ((t & 63) == 0) red[t >> 6] = ssq;
    __syncthreads();
    float tot = red[0] + red[1] + red[2];
    float scale = 1.f / (sqrtf(tot) + tot);
#pragma unroll
    for (int j = 0; j < 6; j++) u[base + t + j * 192] = vals[j] * scale;
}

__global__ __launch_bounds__(1024) void transpose_u(const float* __restrict__ u, float* __restrict__ uT){
    __shared__ float tile[32][33];
    int ki0 = blockIdx.x * 32, b0 = blockIdx.y * 32;
    int tx = threadIdx.x, ty = threadIdx.y;
    int b = b0 + ty;
    if (b < NB) tile[ty][tx] = u[b * 9216 + ki0 + tx];
    __syncthreads();
    int bw = b0 + tx;
    if (bw < NB) uT[(ki0 + ty) * NB + bw] = tile[tx][ty];
}

__global__ void softmax_b(const float* __restrict__ bij, float* __restrict__ c){
    int i = blockIdx.x * 256 + threadIdx.x;
    if (i >= 1152) return;
    float v[10]; float m = -1e30f;
#pragma unroll
    for (int o = 0; o < 10; o++){ v[o] = bij[i * 10 + o]; m = fmaxf(m, v[o]); }
    float sum = 0.f;
#pragma unroll
    for (int o = 0; o < 10; o++){ v[o] = __expf(v[o] - m); sum += v[o]; }
    float inv = 1.f / sum;
#pragma unroll
    for (int o = 0; o < 10; o++) c[i * 10 + o] = v[o] * inv;
}

__global__ void build_cw2(const float* __restrict__ c, const float* __restrict__ Wr, float* __restrict__ cw2){
    int t = blockIdx.x * 256 + threadIdx.x;
    int d = t & 15;
    int ki = (t >> 4) % 9216;
    int o = t / (9216 * 16);
    int k = ki / 1152, i = ki % 1152;
    cw2[t] = c[i * 10 + o] * Wr[(i * 10 + o) * 128 + d * 8 + k];
}

__global__ __launch_bounds__(192) void s_partial(const float* __restrict__ cw2, const float* __restrict__ uT,
                                                 float* __restrict__ part){
    int o = blockIdx.x, kc = blockIdx.y;
    int t = threadIdx.x;
    if (t >= NB) return;
    float acc[16];
#pragma unroll
    for (int d = 0; d < 16; d++) acc[d] = 0.f;
    int ki0 = kc * 512;
    const float* cwp = cw2 + (o * 9216 + ki0) * 16;
    const float* up = uT + ki0 * NB;
    for (int j = 0; j < 512; j++){
        float uv = up[j * NB + t];
#pragma unroll
        for (int d = 0; d < 16; d++) acc[d] += uv * cwp[j * 16 + d];
    }
    float* pp = part + ((o * 18 + kc) * NB + t) * 16;
#pragma unroll
    for (int d = 0; d < 16; d++) pp[d] = acc[d];
}

__global__ void s_reduce(const float* __restrict__ part, float* __restrict__ s){
    int t = blockIdx.x * 256 + threadIdx.x;
    if (t >= 28800) return;
    int d = t & 15, o = (t >> 4) % 10, b = t / 160;
    float acc = 0.f;
    for (int kc = 0; kc < 18; kc++) acc += part[((o * 18 + kc) * NB + b) * 16 + d];
    s[t] = acc;
}

__global__ void v_squash(const float* __restrict__ s, float* __restrict__ v){
    int t = blockIdx.x * 256 + threadIdx.x;
    if (t >= 2880) return;
    int b = t >> 4, d = t & 15;
    const float* sp = s + b * 160 + d;
    float sv[10]; float msq = 0.f;
#pragma unroll
    for (int o = 0; o < 10; o++){ sv[o] = sp[o * 16]; msq += sv[o] * sv[o]; }
    float scale = 1.f / (sqrtf(msq) + msq);
    float* vp = v + b * 160 + d;
#pragma unroll
    for (int o = 0; o < 10; o++) vp[o * 16] = sv[o] * scale;
}

__global__ __launch_bounds__(320) void p_gemm(const float* __restrict__ uT, const float* __restrict__ v,
                                              float* __restrict__ P){
    __shared__ float vs[60 * 160];
    int t = threadIdx.x;
    int o = t % 10, kil = t / 10;
    int ki = blockIdx.x * 32 + kil;
    float acc[16];
#pragma unroll
    for (int d = 0; d < 16; d++) acc[d] = 0.f;
    const float* up = uT + ki * NB;
    for (int b0 = 0; b0 < NB; b0 += 60){
        __syncthreads();
        for (int j = t; j < 9600; j += 320) vs[j] = v[b0 * 160 + j];
        __syncthreads();
        for (int b = 0; b < 60; b++){
            float uv = up[b0 + b];
            const float* vp = &vs[b * 160 + o * 16];
#pragma unroll
            for (int d = 0; d < 16; d++) acc[d] += uv * vp[d];
        }
    }
    float* pp = P + ki * 160 + o * 16;
#pragma unroll
    for (int d = 0; d < 16; d++) pp[d] = acc[d];
}

__global__ void uv_contract(const float* __restrict__ Wr, const float* __restrict__ P, float* __restrict__ bij){
    int t = blockIdx.x * 256 + threadIdx.x;
    if (t >= 11520) return;
    int o = t % 10, i = t / 10;
    const float* wp = Wr + (i * 10 + o) * 128;
    float acc = 0.f;
    for (int k = 0; k < 8; k++){
        const float* pp = P + (k * 1152 + i) * 160 + o * 16;
#pragma unroll
        for (int d = 0; d < 16; d++) acc += wp[d * 8 + k] * pp[d];
    }
    bij[t] += acc * (1.0f / 180.0f);
}

extern "C" void kernel_launch(void* const* d_in, const int* in_sizes, int n_in,
                              void* d_out, int out_size, void* d_ws, size_t ws_size,
                              hipStream_t stream){
    const float* x       = (const float*)d_in[0];
    const float* conv1_w = (const float*)d_in[1];
    const float* conv1_b = (const float*)d_in[2];
    const float* caps_w  = (const float*)d_in[3];
    const float* caps_b  = (const float*)d_in[4];
    const float* Wr      = (const float*)d_in[5];
    float* out = (float*)d_out;

    char* wsb = (char*)d_ws;
    __hip_bfloat16* hTb   = (__hip_bfloat16*)wsb;                 // 18,432,000 bf16
    __hip_bfloat16* bpack = (__hip_bfloat16*)(wsb + 36864000);    //  5,308,416 bf16
    float* u    = (float*)(wsb + 36864000 + 10616832);
    float* uT   = u    + 1658880;
    float* cw2  = uT   + 1658880;
    float* part = cw2  + 1474560;
    float* s    = part + 518400;
    float* P    = s    + 28800;
    float* bij  = P    + 1474560;
    float* c    = bij  + 11520;

    zero_f32<<<45, 256, 0, stream>>>(bij, 11520);
    init_u<<<6480, 256, 0, stream>>>(u, caps_b);
    build_bpack<<<20736, 256, 0, stream>>>(caps_w, bpack);
    conv1_kernel<<<dim3(180, 8), 640, 0, stream>>>(x, conv1_w, conv1_b, hTb);
    capsconv_mfma<<<dim3(45, 9), 768, 0, stream>>>(hTb, bpack, u);
    squash_u<<<1440, 192, 0, stream>>>(u);
    transpose_u<<<dim3(288, 6), dim3(32, 32), 0, stream>>>(u, uT);

    for (int it = 0; it < 3; ++it){
        softmax_b<<<5, 256, 0, stream>>>(bij, c);
        build_cw2<<<5760, 256, 0, stream>>>(c, Wr, cw2);
        s_partial<<<dim3(10, 18), 192, 0, stream>>>(cw2, uT, part);
        s_reduce<<<113, 256, 0, stream>>>(part, s);
        v_squash<<<12, 256, 0, stream>>>(s, out);
        if (it < 2){
            p_gemm<<<288, 320, 0, stream>>>(uT, out, P);
            uv_contract<<<45, 256, 0, stream>>>(Wr, P, bij);
        }
    }
}

// Round 3
// 507.234 us; speedup vs baseline: 4.0250x; 1.5637x over previous
//
#include <hip/hip_runtime.h>
#include <hip/hip_bf16.h>

#define NB 180
typedef __attribute__((ext_vector_type(8))) short short8;
typedef __attribute__((ext_vector_type(4))) float f32x4;
typedef unsigned short ushort_t;

#define WAITV(N) asm volatile("s_waitcnt vmcnt(" #N ")" ::: "memory")

__device__ __forceinline__ void gload16(const void* src, void* lds_base){
    __builtin_amdgcn_global_load_lds(
        (const __attribute__((address_space(1))) unsigned int*)src,
        (__attribute__((address_space(3))) unsigned int*)lds_base, 16, 0, 0);
}

__global__ void zero_f32(float* __restrict__ p, int n){
    int i = blockIdx.x * 256 + threadIdx.x;
    if (i < n) p[i] = 0.f;
}

// caps_w fp32 [oc=256][ic256*81] -> bpack bf16 [gk=(ky*9+kx)*32+ic>>3][oc][j=ic&7]
__global__ void build_bpack(const float* __restrict__ w, __hip_bfloat16* __restrict__ bpack){
    int t = blockIdx.x * 256 + threadIdx.x;   // 5,308,416 total
    int j = t & 7; int oc = (t >> 3) & 255; int gk = t >> 11;
    int kk = gk >> 5, icg = gk & 31;
    float v = w[oc * 20736 + (icg * 8 + j) * 81 + kk];
    bpack[t] = __float2bfloat16(v);
}

// conv1+relu -> hT bf16 [b][y20][x20][oc256]
__global__ __launch_bounds__(640) void conv1_kernel(const float* __restrict__ x, const float* __restrict__ w,
                                                    const float* __restrict__ bias, __hip_bfloat16* __restrict__ hT){
    __shared__ float xs[784];
    __shared__ float ws[32 * 81];
    int b = blockIdx.x, ocg = blockIdx.y;
    int t = threadIdx.x;
    for (int i = t; i < 784; i += 640) xs[i] = x[b * 784 + i];
    for (int i = t; i < 32 * 81; i += 640) ws[i] = w[ocg * 32 * 81 + i];
    __syncthreads();
    int ocl = t & 31, oy = t >> 5;
    int oc = ocg * 32 + ocl;
    float acc[20];
#pragma unroll
    for (int i = 0; i < 20; i++) acc[i] = 0.f;
    for (int ky = 0; ky < 9; ky++){
        float xr[28];
        const float* row = &xs[(oy + ky) * 28];
#pragma unroll
        for (int i = 0; i < 28; i += 4){
            float4 v4 = *(const float4*)(row + i);
            xr[i] = v4.x; xr[i+1] = v4.y; xr[i+2] = v4.z; xr[i+3] = v4.w;
        }
#pragma unroll
        for (int kx = 0; kx < 9; kx++){
            float wv = ws[ocl * 81 + ky * 9 + kx];
#pragma unroll
            for (int ox = 0; ox < 20; ox++) acc[ox] += wv * xr[ox + kx];
        }
    }
    float bv = bias[oc];
#pragma unroll
    for (int ox = 0; ox < 20; ox++){
        float v = acc[ox] + bv;
        v = v > 0.f ? v : 0.f;
        hT[((b * 20 + oy) * 20 + ox) * 256 + oc] = __float2bfloat16(v);
    }
}

// Implicit-GEMM capsconv, pipelined. M=144 (4 batches) x N=256, K-chunk = one ky.
// grid (45, 9), block 768 = 12 waves (3 wm x 4 wn). Dynamic LDS 110592 B:
//   A: 480 px * 8 granules (61440 B), ic-64 rows, XOR f(p)=((x>>1)+6*yy)&7 on granule slot
//   B: 3 x 1024 granules (49152 B), triple-buffered (kx, 32ic) chunks
// 72 steps: s = a*18 + kx*2 + icsub; counted vmcnt, raw barriers. Writes part[ky][b][9216].
__global__ __launch_bounds__(768) void capsconv_mfma(const __hip_bfloat16* __restrict__ hT,
                                                     const __hip_bfloat16* __restrict__ bpack,
                                                     float* __restrict__ part){
    extern __shared__ char smem[];
    ushort_t* hsA = (ushort_t*)smem;                       // 3840 granules
    ushort_t* hsB = (ushort_t*)(smem + 61440);             // 3*1024 granules

    int mt = blockIdx.x, ky = blockIdx.y, b0 = mt * 4;
    int t = threadIdx.x, lane = t & 63, w = t >> 6;
    int wm = w >> 2, wn = w & 3;
    int g = lane >> 4, lr = lane & 15;

    int pb[3], fb[3];
#pragma unroll
    for (int m = 0; m < 3; m++){
        int R = wm * 48 + m * 16 + lr;
        int lb = R / 36, pos = R - lb * 36;
        int oy = pos / 6, ox = pos - oy * 6;
        int yy = lb * 6 + oy;
        pb[m] = yy * 20 + 2 * ox;
        fb[m] = ox + 6 * yy;
    }

    // ---- staging helpers ----
    auto stageA = [&](int a){
#pragma unroll
        for (int rnd = 0; rnd < 5; rnd++){
            int L = rnd * 768 + t;
            int p = L >> 3, sg = L & 7;
            int yy = p / 20, xx = p - yy * 20;
            int lb = yy / 6;
            int y = ky + 2 * (yy - lb * 6);
            int f = ((xx >> 1) + 6 * yy) & 7;
            const __hip_bfloat16* src = hT + ((size_t)(((b0 + lb) * 20 + y) * 20 + xx) * 256
                                             + a * 64 + 8 * (sg ^ f));
            gload16(src, hsA + (size_t)(rnd * 768 + w * 64) * 8);
        }
    };
    auto stageB = [&](int s, int buf){
        if (w < 8){
            int a = s / 18, r = s - a * 18;
            int kx = r >> 1, ics = r & 1;
            int kk = ky * 9 + kx;
            const __hip_bfloat16* src = bpack + (size_t)(kk * 32 + a * 8 + ics * 4) * 256 * 8;
#pragma unroll
            for (int rnd = 0; rnd < 2; rnd++){
                int gi = (w * 2 + rnd) * 64;
                gload16(src + (size_t)(gi + lane) * 8, hsB + (size_t)(buf * 1024 + gi) * 8);
            }
        }
    };

    f32x4 acc[3][4];
#pragma unroll
    for (int m = 0; m < 3; m++)
#pragma unroll
        for (int n = 0; n < 4; n++) acc[m][n] = (f32x4){0.f, 0.f, 0.f, 0.f};

    // prologue: A chunk 0 + B steps 0,1
    stageA(0);
    stageB(0, 0);
    stageB(1, 1);
    if (w < 8) WAITV(2); else WAITV(0);
    __builtin_amdgcn_s_barrier();

    for (int s = 0; s < 72; s++){
        int cur = s % 3;
        int a = s / 18, r = s - a * 18;
        int kx = r >> 1, ics = r & 1;

        if (s + 2 < 72) stageB(s + 2, (s + 2) % 3);

        int K = 4;
        if (s > 0 && r == 0) K = 2;      // new A chunk must be complete
        if (s == 70) K = 2;
        if (s == 71) K = 0;
        if (w < 8){
            if (K == 4) WAITV(4); else if (K == 2) WAITV(2); else WAITV(0);
        } else {
            WAITV(0);
        }
        __builtin_amdgcn_s_barrier();

        // fragment reads
        short8 bf[4];
#pragma unroll
        for (int n = 0; n < 4; n++)
            bf[n] = *(const short8*)(hsB + (size_t)(cur * 1024 + g * 256 + wn * 64 + n * 16 + lr) * 8);
        short8 af[3];
#pragma unroll
        for (int m = 0; m < 3; m++){
            int p = pb[m] + kx;
            int jj = ics * 4 + g;
            int f = (fb[m] + (kx >> 1)) & 7;
            af[m] = *(const short8*)(hsA + (size_t)(p * 8 + (jj ^ f)) * 8);
        }
#pragma unroll
        for (int m = 0; m < 3; m++)
#pragma unroll
            for (int n = 0; n < 4; n++)
                acc[m][n] = __builtin_amdgcn_mfma_f32_16x16x32_bf16(af[m], bf[n], acc[m][n], 0, 0, 0);

        __builtin_amdgcn_s_barrier();
        if (r == 17 && a < 3) stageA(a + 1);   // after all waves finished reading old A
    }

    // ---- epilogue: LDS transpose to [lb][oc][pos], coalesced stores ----
    float* tl = (float*)smem;                  // 256*37 f32 = 37888 B
    size_t pbase = (size_t)(ky * 180 + mt * 4) * 9216;
    for (int lb = 0; lb < 4; lb++){
        int rlo = lb * 36, rhi = rlo + 36;
#pragma unroll
        for (int m = 0; m < 3; m++){
            int Rb = wm * 48 + m * 16 + g * 4;
#pragma unroll
            for (int n = 0; n < 4; n++){
                int oc = wn * 64 + n * 16 + lr;
#pragma unroll
                for (int rg = 0; rg < 4; rg++){
                    int row = Rb + rg;
                    if (row >= rlo && row < rhi)
                        tl[oc * 37 + (row - rlo)] = acc[m][n][rg];
                }
            }
        }
        __builtin_amdgcn_s_barrier();
#pragma unroll
        for (int j = 0; j < 3; j++){
            int flat = t * 12 + j * 4;
            float4 vv;
            vv.x = tl[((flat    ) / 36) * 37 + (flat    ) % 36];
            vv.y = tl[((flat + 1) / 36) * 37 + (flat + 1) % 36];
            vv.z = tl[((flat + 2) / 36) * 37 + (flat + 2) % 36];
            vv.w = tl[((flat + 3) / 36) * 37 + (flat + 3) % 36];
            *(float4*)&part[pbase + (size_t)lb * 9216 + flat] = vv;
        }
        __builtin_amdgcn_s_barrier();
    }
}

// reduce 9 ky-partials + bias, then squash over each (b,k) 1152-block -> u
__global__ __launch_bounds__(192) void reduce_squash(const float* __restrict__ part,
                                                     const float* __restrict__ caps_b,
                                                     float* __restrict__ u){
    __shared__ float red[3];
    int bk = blockIdx.x;
    int b = bk >> 3, k = bk & 7;
    int t = threadIdx.x;
    size_t base = (size_t)k * 1152;
    float vals[6];
    float ssq = 0.f;
#pragma unroll
    for (int j = 0; j < 6; j++){
        int i = t + j * 192;
        int oc = k * 32 + i / 36;
        float v = caps_b[oc];
#pragma unroll
        for (int kyi = 0; kyi < 9; kyi++)
            v += part[(size_t)(kyi * 180 + b) * 9216 + base + i];
        vals[j] = v; ssq += v * v;
    }
#pragma unroll
    for (int off = 32; off; off >>= 1) ssq += __shfl_down(ssq, off, 64);
    if ((t & 63) == 0) red[t >> 6] = ssq;
    __syncthreads();
    float tot = red[0] + red[1] + red[2];
    float scale = 1.f / (sqrtf(tot) + tot);
#pragma unroll
    for (int j = 0; j < 6; j++)
        u[(size_t)b * 9216 + base + t + j * 192] = vals[j] * scale;
}

__global__ __launch_bounds__(1024) void transpose_u(const float* __restrict__ u, float* __restrict__ uT){
    __shared__ float tile[32][33];
    int ki0 = blockIdx.x * 32, b0 = blockIdx.y * 32;
    int tx = threadIdx.x, ty = threadIdx.y;
    int b = b0 + ty;
    if (b < NB) tile[ty][tx] = u[(size_t)b * 9216 + ki0 + tx];
    __syncthreads();
    int bw = b0 + tx;
    if (bw < NB) uT[(size_t)(ki0 + ty) * NB + bw] = tile[tx][ty];
}

__global__ void softmax_b(const float* __restrict__ bij, float* __restrict__ c){
    int i = blockIdx.x * 256 + threadIdx.x;
    if (i >= 1152) return;
    float v[10]; float m = -1e30f;
#pragma unroll
    for (int o = 0; o < 10; o++){ v[o] = bij[i * 10 + o]; m = fmaxf(m, v[o]); }
    float sum = 0.f;
#pragma unroll
    for (int o = 0; o < 10; o++){ v[o] = __expf(v[o] - m); sum += v[o]; }
    float inv = 1.f / sum;
#pragma unroll
    for (int o = 0; o < 10; o++) c[i * 10 + o] = v[o] * inv;
}

__global__ void build_cw2(const float* __restrict__ c, const float* __restrict__ Wr, float* __restrict__ cw2){
    int t = blockIdx.x * 256 + threadIdx.x;
    int d = t & 15;
    int ki = (t >> 4) % 9216;
    int o = t / (9216 * 16);
    int k = ki / 1152, i = ki % 1152;
    cw2[t] = c[i * 10 + o] * Wr[(i * 10 + o) * 128 + d * 8 + k];
}

__global__ __launch_bounds__(192) void s_partial(const float* __restrict__ cw2, const float* __restrict__ uT,
                                                 float* __restrict__ part){
    int o = blockIdx.x, kc = blockIdx.y;
    int t = threadIdx.x;
    if (t >= NB) return;
    float acc[16];
#pragma unroll
    for (int d = 0; d < 16; d++) acc[d] = 0.f;
    int ki0 = kc * 512;
    const float* cwp = cw2 + (size_t)(o * 9216 + ki0) * 16;
    const float* up = uT + (size_t)ki0 * NB;
    for (int j = 0; j < 512; j++){
        float uv = up[j * NB + t];
#pragma unroll
        for (int d = 0; d < 16; d++) acc[d] += uv * cwp[j * 16 + d];
    }
    float* pp = part + ((size_t)(o * 18 + kc) * NB + t) * 16;
#pragma unroll
    for (int d = 0; d < 16; d++) pp[d] = acc[d];
}

__global__ void s_reduce(const float* __restrict__ part, float* __restrict__ s){
    int t = blockIdx.x * 256 + threadIdx.x;
    if (t >= 28800) return;
    int d = t & 15, o = (t >> 4) % 10, b = t / 160;
    float acc = 0.f;
    for (int kc = 0; kc < 18; kc++) acc += part[((size_t)(o * 18 + kc) * NB + b) * 16 + d];
    s[t] = acc;
}

__global__ void v_squash(const float* __restrict__ s, float* __restrict__ v){
    int t = blockIdx.x * 256 + threadIdx.x;
    if (t >= 2880) return;
    int b = t >> 4, d = t & 15;
    const float* sp = s + b * 160 + d;
    float sv[10]; float msq = 0.f;
#pragma unroll
    for (int o = 0; o < 10; o++){ sv[o] = sp[o * 16]; msq += sv[o] * sv[o]; }
    float scale = 1.f / (sqrtf(msq) + msq);
    float* vp = v + b * 160 + d;
#pragma unroll
    for (int o = 0; o < 10; o++) vp[o * 16] = sv[o] * scale;
}

__global__ __launch_bounds__(320) void p_gemm(const float* __restrict__ uT, const float* __restrict__ v,
                                              float* __restrict__ P){
    __shared__ float vs[60 * 160];
    int t = threadIdx.x;
    int o = t % 10, kil = t / 10;
    int ki = blockIdx.x * 32 + kil;
    float acc[16];
#pragma unroll
    for (int d = 0; d < 16; d++) acc[d] = 0.f;
    const float* up = uT + (size_t)ki * NB;
    for (int b0 = 0; b0 < NB; b0 += 60){
        __syncthreads();
        for (int j = t; j < 9600; j += 320) vs[j] = v[b0 * 160 + j];
        __syncthreads();
        for (int b = 0; b < 60; b++){
            float uv = up[b0 + b];
            const float* vp = &vs[b * 160 + o * 16];
#pragma unroll
            for (int d = 0; d < 16; d++) acc[d] += uv * vp[d];
        }
    }
    float* pp = P + (size_t)ki * 160 + o * 16;
#pragma unroll
    for (int d = 0; d < 16; d++) pp[d] = acc[d];
}

__global__ void uv_contract(const float* __restrict__ Wr, const float* __restrict__ P, float* __restrict__ bij){
    int t = blockIdx.x * 256 + threadIdx.x;
    if (t >= 11520) return;
    int o = t % 10, i = t / 10;
    const float* wp = Wr + (i * 10 + o) * 128;
    float acc = 0.f;
    for (int k = 0; k < 8; k++){
        const float* pp = P + (size_t)(k * 1152 + i) * 160 + o * 16;
#pragma unroll
        for (int d = 0; d < 16; d++) acc += wp[d * 8 + k] * pp[d];
    }
    bij[t] += acc * (1.0f / 180.0f);
}

extern "C" void kernel_launch(void* const* d_in, const int* in_sizes, int n_in,
                              void* d_out, int out_size, void* d_ws, size_t ws_size,
                              hipStream_t stream){
    const float* x       = (const float*)d_in[0];
    const float* conv1_w = (const float*)d_in[1];
    const float* conv1_b = (const float*)d_in[2];
    const float* caps_w  = (const float*)d_in[3];
    const float* caps_b  = (const float*)d_in[4];
    const float* Wr      = (const float*)d_in[5];
    float* out = (float*)d_out;

    char* wsb = (char*)d_ws;
    __hip_bfloat16* hTb   = (__hip_bfloat16*)wsb;                  // 36,864,000 B
    __hip_bfloat16* bpack = (__hip_bfloat16*)(wsb + 36864000);     // 10,616,832 B
    float* part = (float*)(wsb + 36864000 + 10616832);             // 59,719,680 B (9*180*9216 f32)
    float* u    = part + 14929920;                                 //  6,635,520 B
    float* uT   = u + 1658880;                                     //  6,635,520 B  (total 120.47 MB)

    // routing scratch aliases 'part' (dead after reduce_squash)
    float* cw2   = part;
    float* partS = cw2 + 1474560;
    float* s     = partS + 518400;
    float* P     = s + 28800;
    float* bij   = P + 1474560;
    float* c     = bij + 11520;

    hipFuncSetAttribute((const void*)capsconv_mfma,
                        hipFuncAttributeMaxDynamicSharedMemorySize, 110592);

    build_bpack<<<20736, 256, 0, stream>>>(caps_w, bpack);
    conv1_kernel<<<dim3(180, 8), 640, 0, stream>>>(x, conv1_w, conv1_b, hTb);
    capsconv_mfma<<<dim3(45, 9), 768, 110592, stream>>>(hTb, bpack, part);
    reduce_squash<<<1440, 192, 0, stream>>>(part, caps_b, u);
    transpose_u<<<dim3(288, 6), dim3(32, 32), 0, stream>>>(u, uT);
    zero_f32<<<45, 256, 0, stream>>>(bij, 11520);   // after part is dead (aliased)

    for (int it = 0; it < 3; ++it){
        softmax_b<<<5, 256, 0, stream>>>(bij, c);
        build_cw2<<<5760, 256, 0, stream>>>(c, Wr, cw2);
        s_partial<<<dim3(10, 18), 192, 0, stream>>>(cw2, uT, partS);
        s_reduce<<<113, 256, 0, stream>>>(partS, s);
        v_squash<<<12, 256, 0, stream>>>(s, out);
        if (it < 2){
            p_gemm<<<288, 320, 0, stream>>>(uT, out, P);
            uv_contract<<<45, 256, 0, stream>>>(Wr, P, bij);
        }
    }
}

// Round 4
// 383.342 us; speedup vs baseline: 5.3258x; 1.3232x over previous
//
#include <hip/hip_runtime.h>
#include <hip/hip_bf16.h>

#define NB 180
typedef __attribute__((ext_vector_type(8))) short short8;
typedef __attribute__((ext_vector_type(4))) float f32x4;
typedef unsigned short ushort_t;

__device__ __forceinline__ void gload16(const void* src, void* lds_base){
    __builtin_amdgcn_global_load_lds(
        (const __attribute__((address_space(1))) unsigned int*)src,
        (__attribute__((address_space(3))) unsigned int*)lds_base, 16, 0, 0);
}

// caps_w fp32 [oc=256][ic256*81] -> bpack bf16 [gk=(ky*9+kx)*32+ic>>3][oc][j=ic&7]
__global__ void build_bpack(const float* __restrict__ w, __hip_bfloat16* __restrict__ bpack){
    int t = blockIdx.x * 256 + threadIdx.x;   // 5,308,416 total
    int j = t & 7; int oc = (t >> 3) & 255; int gk = t >> 11;
    int kk = gk >> 5, icg = gk & 31;
    float v = w[oc * 20736 + (icg * 8 + j) * 81 + kk];
    bpack[t] = __float2bfloat16(v);
}

// conv1+relu -> hT bf16 [b][y20][x20][oc256]
__global__ __launch_bounds__(640) void conv1_kernel(const float* __restrict__ x, const float* __restrict__ w,
                                                    const float* __restrict__ bias, __hip_bfloat16* __restrict__ hT){
    __shared__ float xs[784];
    __shared__ float ws[32 * 81];
    int b = blockIdx.x, ocg = blockIdx.y;
    int t = threadIdx.x;
    for (int i = t; i < 784; i += 640) xs[i] = x[b * 784 + i];
    for (int i = t; i < 32 * 81; i += 640) ws[i] = w[ocg * 32 * 81 + i];
    __syncthreads();
    int ocl = t & 31, oy = t >> 5;
    int oc = ocg * 32 + ocl;
    float acc[20];
#pragma unroll
    for (int i = 0; i < 20; i++) acc[i] = 0.f;
    for (int ky = 0; ky < 9; ky++){
        float xr[28];
        const float* row = &xs[(oy + ky) * 28];
#pragma unroll
        for (int i = 0; i < 28; i += 4){
            float4 v4 = *(const float4*)(row + i);
            xr[i] = v4.x; xr[i+1] = v4.y; xr[i+2] = v4.z; xr[i+3] = v4.w;
        }
#pragma unroll
        for (int kx = 0; kx < 9; kx++){
            float wv = ws[ocl * 81 + ky * 9 + kx];
#pragma unroll
            for (int ox = 0; ox < 20; ox++) acc[ox] += wv * xr[ox + kx];
        }
    }
    float bv = bias[oc];
#pragma unroll
    for (int ox = 0; ox < 20; ox++){
        float v = acc[ox] + bv;
        v = v > 0.f ? v : 0.f;
        hT[((b * 20 + oy) * 20 + ox) * 256 + oc] = __float2bfloat16(v);
    }
}

// Implicit-GEMM capsconv. Block = 144x256 (4 batches), 4 waves, wave-tile 144x64.
// A (activations) in LDS 61.4KB per 64-ic chunk, XOR-swizzled; B (weights) global->regs,
// 1-step register prefetch. Barriers only at 4 A-chunk boundaries. 2 blocks/CU.
// grid (45, 9): all 405 blocks co-resident. Writes part[ky][b][oc*36+pos].
__global__ __launch_bounds__(256, 2) void capsconv_mfma(const __hip_bfloat16* __restrict__ hT,
                                                        const __hip_bfloat16* __restrict__ bpack,
                                                        float* __restrict__ part){
    extern __shared__ char smem[];               // 61440 B
    ushort_t* hsA = (ushort_t*)smem;

    int mt = blockIdx.x, ky = blockIdx.y, b0 = mt * 4;
    int t = threadIdx.x, lane = t & 63, wn = t >> 6;
    int g = lane >> 4, lr = lane & 15;

    int pb[9], fb[9];
#pragma unroll
    for (int m = 0; m < 9; m++){
        int R = m * 16 + lr;
        int lb = R / 36, pos = R - lb * 36;
        int oy = pos / 6, ox = pos - oy * 6;
        int yy = lb * 6 + oy;
        pb[m] = yy * 20 + 2 * ox;
        fb[m] = ox + 6 * yy;
    }

    auto stageA = [&](int a){
#pragma unroll
        for (int rnd = 0; rnd < 15; rnd++){
            int L = rnd * 256 + t;               // granule 0..3839
            int p = L >> 3, sg = L & 7;
            int yy = p / 20, xx = p - yy * 20;
            int lb = yy / 6;
            int y = ky + 2 * (yy - lb * 6);
            int f = ((xx >> 1) + 6 * yy) & 7;
            const __hip_bfloat16* src = hT + ((size_t)(((b0 + lb) * 20 + y) * 20 + xx) * 256
                                             + a * 64 + 8 * (sg ^ f));
            gload16(src, hsA + (size_t)(rnd * 256 + (t & ~63)) * 8);
        }
    };
    auto loadB = [&](int s, short8* bf){
        int a = s / 18, r = s - a * 18;
        int kx = r >> 1, ics = r & 1;
        int ksg = (ky * 9 + kx) * 8 + 2 * a + ics;
        const __hip_bfloat16* base = bpack + (size_t)(ksg * 4 + g) * 256 * 8;
#pragma unroll
        for (int n = 0; n < 4; n++)
            bf[n] = *(const short8*)(base + (size_t)(wn * 64 + n * 16 + lr) * 8);
    };

    f32x4 acc[9][4];
#pragma unroll
    for (int m = 0; m < 9; m++)
#pragma unroll
        for (int n = 0; n < 4; n++) acc[m][n] = (f32x4){0.f, 0.f, 0.f, 0.f};

    short8 bcur[4], bnxt[4];
    stageA(0);
    loadB(0, bcur);
    __syncthreads();

    for (int a = 0; a < 4; a++){
#pragma unroll 2
        for (int r = 0; r < 18; r++){
            int s = a * 18 + r;
            int kx = r >> 1, ics = r & 1;
            if (s < 71) loadB(s + 1, bnxt);
            int jj = ics * 4 + g;
#pragma unroll
            for (int m = 0; m < 9; m++){
                int p = pb[m] + kx;
                int f = (fb[m] + (kx >> 1)) & 7;
                short8 af = *(const short8*)(hsA + (size_t)(p * 8 + (jj ^ f)) * 8);
#pragma unroll
                for (int n = 0; n < 4; n++)
                    acc[m][n] = __builtin_amdgcn_mfma_f32_16x16x32_bf16(af, bcur[n], acc[m][n], 0, 0, 0);
            }
#pragma unroll
            for (int n = 0; n < 4; n++) bcur[n] = bnxt[n];
        }
        if (a < 3){
            __syncthreads();     // all waves done reading chunk a
            stageA(a + 1);
            __syncthreads();     // drains gload16s (vmcnt 0) + visibility
        }
    }

    // Epilogue: per-lb LDS transpose tile tl[pos 36][oc 256 pad 260], conflict-free.
    float* tl = (float*)smem;
    size_t pbase = ((size_t)ky * 180 + b0) * 9216;
    for (int lb = 0; lb < 4; lb++){
        int rlo = lb * 36;
        __syncthreads();
#pragma unroll
        for (int m = 0; m < 9; m++){
#pragma unroll
            for (int n = 0; n < 4; n++){
                int oc = wn * 64 + n * 16 + lr;
#pragma unroll
                for (int rg = 0; rg < 4; rg++){
                    int row = m * 16 + g * 4 + rg;
                    if (row >= rlo && row < rlo + 36)
                        tl[(row - rlo) * 260 + oc] = acc[m][n][rg];
                }
            }
        }
        __syncthreads();
#pragma unroll
        for (int j = 0; j < 9; j++){
            int pos = j * 4;
            float4 vv;
            vv.x = tl[(pos    ) * 260 + t];
            vv.y = tl[(pos + 1) * 260 + t];
            vv.z = tl[(pos + 2) * 260 + t];
            vv.w = tl[(pos + 3) * 260 + t];
            *(float4*)&part[pbase + (size_t)lb * 9216 + t * 36 + pos] = vv;
        }
    }
}

// reduce 9 ky-partials + bias, then squash over each (b,k) 1152-block -> u
__global__ __launch_bounds__(192) void reduce_squash(const float* __restrict__ part,
                                                     const float* __restrict__ caps_b,
                                                     float* __restrict__ u){
    __shared__ float red[3];
    int bk = blockIdx.x;
    int b = bk >> 3, k = bk & 7;
    int t = threadIdx.x;
    size_t base = (size_t)k * 1152;
    float vals[6];
    float ssq = 0.f;
#pragma unroll
    for (int j = 0; j < 6; j++){
        int i = t + j * 192;
        int oc = k * 32 + i / 36;
        float v = caps_b[oc];
#pragma unroll
        for (int kyi = 0; kyi < 9; kyi++)
            v += part[(size_t)(kyi * 180 + b) * 9216 + base + i];
        vals[j] = v; ssq += v * v;
    }
#pragma unroll
    for (int off = 32; off; off >>= 1) ssq += __shfl_down(ssq, off, 64);
    if ((t & 63) == 0) red[t >> 6] = ssq;
    __syncthreads();
    float tot = red[0] + red[1] + red[2];
    float scale = 1.f / (sqrtf(tot) + tot);
#pragma unroll
    for (int j = 0; j < 6; j++)
        u[(size_t)b * 9216 + base + t + j * 192] = vals[j] * scale;
}

__global__ __launch_bounds__(1024) void transpose_u(const float* __restrict__ u, float* __restrict__ uT){
    __shared__ float tile[32][33];
    int ki0 = blockIdx.x * 32, b0 = blockIdx.y * 32;
    int tx = threadIdx.x, ty = threadIdx.y;
    int b = b0 + ty;
    if (b < NB) tile[ty][tx] = u[(size_t)b * 9216 + ki0 + tx];
    __syncthreads();
    int bw = b0 + tx;
    if (bw < NB) uT[(size_t)(ki0 + ty) * NB + bw] = tile[tx][ty];
}

// fused softmax(bij) * W -> cw2[o][ki][d]; iter 1 uses c = 0.1 exactly.
__global__ void build_cw2_f(const float* __restrict__ bij, const float* __restrict__ Wr,
                            float* __restrict__ cw2, int first){
    int t = blockIdx.x * 256 + threadIdx.x;   // 1,474,560
    int d = t & 15;
    int ki = (t >> 4) % 9216;
    int o = t / 147456;
    int k = ki / 1152, i = ki - k * 1152;
    float c;
    if (first){
        c = 0.1f;
    } else {
        float v[10]; float mx = -1e30f;
#pragma unroll
        for (int q = 0; q < 10; q++){ v[q] = bij[i * 10 + q]; mx = fmaxf(mx, v[q]); }
        float sum = 0.f;
#pragma unroll
        for (int q = 0; q < 10; q++){ v[q] = __expf(v[q] - mx); sum += v[q]; }
        c = v[o] / sum;
    }
    cw2[t] = c * Wr[(i * 10 + o) * 128 + d * 8 + k];
}

// split-K partials: part36[o][kc][b][d] = sum over 256 ki of cw2[o][ki][d]*uT[ki][b]
__global__ __launch_bounds__(192) void s_partial(const float* __restrict__ cw2, const float* __restrict__ uT,
                                                 float* __restrict__ part36){
    int o = blockIdx.x, kc = blockIdx.y;
    int t = threadIdx.x;
    if (t >= NB) return;
    float acc[16];
#pragma unroll
    for (int d = 0; d < 16; d++) acc[d] = 0.f;
    int ki0 = kc * 256;
    const float* cwp = cw2 + (size_t)(o * 9216 + ki0) * 16;
    const float* up = uT + (size_t)ki0 * NB;
    for (int j = 0; j < 256; j++){
        float uv = up[j * NB + t];
#pragma unroll
        for (int d = 0; d < 16; d++) acc[d] += uv * cwp[j * 16 + d];
    }
    float* pp = part36 + ((size_t)(o * 36 + kc) * NB + t) * 16;
#pragma unroll
    for (int d = 0; d < 16; d++) pp[d] = acc[d];
}

// fused: s[b][o][d] = sum_kc part36 ; v = s / (sqrt(msq)+msq), msq over o
__global__ __launch_bounds__(192) void sred_vsq(const float* __restrict__ part36, float* __restrict__ v){
    __shared__ float sv[160];
    __shared__ float sc[16];
    int b = blockIdx.x, t = threadIdx.x;
    float s = 0.f;
    if (t < 160){
        for (int kc = 0; kc < 36; kc++)
            s += part36[((size_t)((t >> 4) * 36 + kc) * NB + b) * 16 + (t & 15)];
        sv[t] = s;
    }
    __syncthreads();
    if (t < 16){
        float m = 0.f;
#pragma unroll
        for (int o = 0; o < 10; o++){ float x = sv[o * 16 + t]; m += x * x; }
        sc[t] = 1.f / (sqrtf(m) + m);
    }
    __syncthreads();
    if (t < 160) v[b * 160 + t] = s * sc[t & 15];
}

__global__ __launch_bounds__(320) void p_gemm(const float* __restrict__ uT, const float* __restrict__ v,
                                              float* __restrict__ P){
    __shared__ float vs[60 * 160];
    int t = threadIdx.x;
    int o = t % 10, kil = t / 10;
    int ki = blockIdx.x * 32 + kil;
    float acc[16];
#pragma unroll
    for (int d = 0; d < 16; d++) acc[d] = 0.f;
    const float* up = uT + (size_t)ki * NB;
    for (int b0 = 0; b0 < NB; b0 += 60){
        __syncthreads();
        for (int j = t; j < 9600; j += 320) vs[j] = v[b0 * 160 + j];
        __syncthreads();
        for (int b = 0; b < 60; b++){
            float uv = up[b0 + b];
            const float* vp = &vs[b * 160 + o * 16];
#pragma unroll
            for (int d = 0; d < 16; d++) acc[d] += uv * vp[d];
        }
    }
    float* pp = P + (size_t)ki * 160 + o * 16;
#pragma unroll
    for (int d = 0; d < 16; d++) pp[d] = acc[d];
}

__global__ void uv_contract(const float* __restrict__ Wr, const float* __restrict__ P,
                            float* __restrict__ bij, int first){
    int t = blockIdx.x * 256 + threadIdx.x;
    if (t >= 11520) return;
    int o = t % 10, i = t / 10;
    const float* wp = Wr + (i * 10 + o) * 128;
    float acc = 0.f;
    for (int k = 0; k < 8; k++){
        const float* pp = P + (size_t)(k * 1152 + i) * 160 + o * 16;
#pragma unroll
        for (int d = 0; d < 16; d++) acc += wp[d * 8 + k] * pp[d];
    }
    float val = acc * (1.0f / 180.0f);
    if (first) bij[t] = val; else bij[t] += val;
}

extern "C" void kernel_launch(void* const* d_in, const int* in_sizes, int n_in,
                              void* d_out, int out_size, void* d_ws, size_t ws_size,
                              hipStream_t stream){
    const float* x       = (const float*)d_in[0];
    const float* conv1_w = (const float*)d_in[1];
    const float* conv1_b = (const float*)d_in[2];
    const float* caps_w  = (const float*)d_in[3];
    const float* caps_b  = (const float*)d_in[4];
    const float* Wr      = (const float*)d_in[5];
    float* out = (float*)d_out;

    char* wsb = (char*)d_ws;
    __hip_bfloat16* hTb   = (__hip_bfloat16*)wsb;                  // 36,864,000 B
    __hip_bfloat16* bpack = (__hip_bfloat16*)(wsb + 36864000);     // 10,616,832 B
    float* part = (float*)(wsb + 36864000 + 10616832);             // 59,719,680 B (9*180*9216 f32)
    float* u    = part + 14929920;                                 //  6,635,520 B
    float* uT   = u + 1658880;                                     //  6,635,520 B  (total 120.47 MB)

    // routing scratch aliases 'part' (dead after reduce_squash)
    float* cw2    = part;
    float* part36 = cw2 + 1474560;
    float* P      = part36 + 1036800;
    float* bij    = P + 1474560;

    hipFuncSetAttribute((const void*)capsconv_mfma,
                        hipFuncAttributeMaxDynamicSharedMemorySize, 61440);

    build_bpack<<<20736, 256, 0, stream>>>(caps_w, bpack);
    conv1_kernel<<<dim3(180, 8), 640, 0, stream>>>(x, conv1_w, conv1_b, hTb);
    capsconv_mfma<<<dim3(45, 9), 256, 61440, stream>>>(hTb, bpack, part);
    reduce_squash<<<1440, 192, 0, stream>>>(part, caps_b, u);
    transpose_u<<<dim3(288, 6), dim3(32, 32), 0, stream>>>(u, uT);

    for (int it = 0; it < 3; ++it){
        build_cw2_f<<<5760, 256, 0, stream>>>(bij, Wr, cw2, it == 0 ? 1 : 0);
        s_partial<<<dim3(10, 36), 192, 0, stream>>>(cw2, uT, part36);
        sred_vsq<<<180, 192, 0, stream>>>(part36, out);
        if (it < 2){
            p_gemm<<<288, 320, 0, stream>>>(uT, out, P);
            uv_contract<<<45, 256, 0, stream>>>(Wr, P, bij, it == 0 ? 1 : 0);
        }
    }
}